// Round 3
// baseline (208.359 us; speedup 1.0000x reference)
//
#include <hip/hip_runtime.h>
#include <math.h>

#define S_LEN 2048
#define B_SZ 2

typedef __bf16 bf16_8 __attribute__((ext_vector_type(8)));
typedef float  f32_4  __attribute__((ext_vector_type(4)));

__device__ __forceinline__ unsigned short ftob(float f) {
  union { __bf16 h; unsigned short u; } cv;
  cv.h = (__bf16)f;              // fptrunc -> RNE
  return cv.u;
}

// async global->LDS, 16B per lane. LDS dest must be wave-uniform base + lane*16.
__device__ __forceinline__ void gll16(const unsigned short* g, unsigned short* l) {
  __builtin_amdgcn_global_load_lds(
      (const __attribute__((address_space(1))) unsigned int*)g,
      (__attribute__((address_space(3))) unsigned int*)l, 16, 0, 0);
}

// fold 1/sqrt(64) * log2(e) into Q at projection -> softmax in exp2 domain
#define QSCALE (0.125f * 1.44269504f)

// K/V tile images: dense 64x64 bf16 (4096 shorts = 8 KB), 16B-chunk XOR
// swizzle: element (row, col) at row*64 + ((col>>3) ^ (row&7))*8 + (col&7).
// K image rows = key, cols = d. V image rows = d, cols = key.
// The image layout IS the fragment layout -> flash reads frags straight from
// L2 (XCD-pinned, 512 KB per (b,g)) with no LDS staging and no barriers.

// ---------------------------------------------------------------------------
// 32x32 transpose+convert tile helper: W[K=1024][N] fp32 -> Wt[N][1024] bf16.
// ---------------------------------------------------------------------------
__device__ __forceinline__ void tr_tile(const float* __restrict__ W,
                                        unsigned short* __restrict__ Wt,
                                        int N, int bx, int by, float (*T)[33])
{
  const int k0 = by * 32, n0 = bx * 32;
  const int r = threadIdx.x >> 3, c4 = (threadIdx.x & 7) * 4;
  const float4 v = *(const float4*)&W[(size_t)(k0 + r) * N + n0 + c4];
  T[r][c4 + 0] = v.x; T[r][c4 + 1] = v.y;
  T[r][c4 + 2] = v.z; T[r][c4 + 3] = v.w;
  __syncthreads();
  ushort4 o;
  o.x = ftob(T[c4 + 0][r]); o.y = ftob(T[c4 + 1][r]);
  o.z = ftob(T[c4 + 2][r]); o.w = ftob(T[c4 + 3][r]);
  *(ushort4*)&Wt[(size_t)(n0 + r) * 1024 + k0 + c4] = o;
}

// ---------------------------------------------------------------------------
// prep: [0,1024) wq->wqkvt | [1024,1280) wk | [1280,1536) wv |
//       [1536,2560) wo->wot | [2560,3584) x fp32->bf16
// ---------------------------------------------------------------------------
__global__ __launch_bounds__(256) void prep(
    const float* __restrict__ x, const float* __restrict__ wq,
    const float* __restrict__ wk, const float* __restrict__ wv,
    const float* __restrict__ wo,
    unsigned short* __restrict__ xb, unsigned short* __restrict__ wqkvt,
    unsigned short* __restrict__ wot)
{
  __shared__ float T[32][33];
  const int idx = blockIdx.x;
  if (idx < 1024) {
    tr_tile(wq, wqkvt, 1024, idx & 31, idx >> 5, T);
  } else if (idx < 1280) {
    const int i = idx - 1024;
    tr_tile(wk, wqkvt + 1024 * 1024, 256, i & 7, i >> 3, T);
  } else if (idx < 1536) {
    const int i = idx - 1280;
    tr_tile(wv, wqkvt + 1280 * 1024, 256, i & 7, i >> 3, T);
  } else if (idx < 2560) {
    const int i = idx - 1536;
    tr_tile(wo, wot, 1024, i & 31, i >> 5, T);
  } else {
    const int i = idx - 2560;
#pragma unroll
    for (int j = 0; j < 4; ++j) {
      const int id = i * 1024 + (int)threadIdx.x + j * 256;
      const float4 v = ((const float4*)x)[id];
      ushort4 o;
      o.x = ftob(v.x); o.y = ftob(v.y); o.z = ftob(v.z); o.w = ftob(v.w);
      ((ushort4*)xb)[id] = o;
    }
  }
}

// ---------------------------------------------------------------------------
// 64x128 GEMM core, 2-phase: BK=64 (stored as two BK=32 panels, preserving the
// m97 bank layout), double-buffered LDS (2 x 24 KB), global_load_lds w16,
// ONE barrier per K-step. STAGE(next) is issued before ds_read+MFMA of the
// current buffer, so the 6 in-flight loads drain under compute; the barrier's
// vmcnt(0) then covers the prefetch. 16 steps, 17 barriers total (vs 64).
// Buffer layout (shorts, per 12288-buf): [0,2048) A k0 | [2048,4096) A k1 |
// [4096,8192) B k0 (128 rows) | [8192,12288) B k1.
// ---------------------------------------------------------------------------
#define G64DB_STAGE(A_, B_, bo_, k0_)                                           \
  do {                                                                          \
    const int r = tid >> 2, o8 = (tid & 3) * 8;                                 \
    gll16(&A_[(size_t)(bm + r) * 1024 + (k0_) + o8], &sm[(bo_) + tid * 8]);     \
    gll16(&A_[(size_t)(bm + r) * 1024 + (k0_) + 32 + o8],                       \
          &sm[(bo_) + 2048 + tid * 8]);                                         \
    gll16(&B_[(size_t)(bn0 * 128 + r) * 1024 + (k0_) + o8],                     \
          &sm[(bo_) + 4096 + tid * 8]);                                         \
    gll16(&B_[(size_t)(bn0 * 128 + r + 64) * 1024 + (k0_) + o8],                \
          &sm[(bo_) + 6144 + tid * 8]);                                         \
    gll16(&B_[(size_t)(bn0 * 128 + r) * 1024 + (k0_) + 32 + o8],                \
          &sm[(bo_) + 8192 + tid * 8]);                                         \
    gll16(&B_[(size_t)(bn0 * 128 + r + 64) * 1024 + (k0_) + 32 + o8],           \
          &sm[(bo_) + 10240 + tid * 8]);                                        \
  } while (0)

#define G64DB_KLOOP(A_, B_)                                                     \
  G64DB_STAGE(A_, B_, 0, 0);                                                    \
  __syncthreads();                                                              \
  for (int s = 0; s < 16; ++s) {                                                \
    const int bo = (s & 1) * 12288;                                             \
    if (s < 15) G64DB_STAGE(A_, B_, bo ^ 12288, (s + 1) * 64);                  \
    bf16_8 af[2][2], bf[2][4];                                                  \
    _Pragma("unroll")                                                           \
    for (int ks = 0; ks < 2; ++ks) {                                            \
      _Pragma("unroll")                                                         \
      for (int mt = 0; mt < 2; ++mt)                                            \
        af[ks][mt] = *(const bf16_8*)&sm[bo + ks * 2048 +                       \
                                         (mh + mt * 16 + l16) * 32 + quad * 8]; \
      _Pragma("unroll")                                                         \
      for (int nt = 0; nt < 4; ++nt)                                            \
        bf[ks][nt] = *(const bf16_8*)&sm[bo + 4096 + ks * 4096 +                \
                                         (nh + nt * 16 + l16) * 32 + quad * 8]; \
    }                                                                           \
    _Pragma("unroll")                                                           \
    for (int ks = 0; ks < 2; ++ks)                                              \
      _Pragma("unroll")                                                         \
      for (int mt = 0; mt < 2; ++mt)                                            \
        _Pragma("unroll")                                                       \
        for (int nt = 0; nt < 4; ++nt)                                          \
          acc[mt][nt] = __builtin_amdgcn_mfma_f32_16x16x32_bf16(                \
              af[ks][mt], bf[ks][nt], acc[mt][nt], 0, 0, 0);                    \
    __syncthreads();                                                            \
  }

// ---------------------------------------------------------------------------
// Fused QKV GEMM: [4096][1536] = xb @ wqkvt^T. BM=64, BN=128, grid (12,64).
// Epilogue by column block: bn0 0..7 Q rope+scale -> qb; 8..9 K rope -> Kimg
// (swizzled); 10..11 V -> LDS transpose -> Vimg (swizzled, b128 stores).
// ---------------------------------------------------------------------------
__global__ __launch_bounds__(256, 3) void gemm_qkv(
    const unsigned short* __restrict__ A, const unsigned short* __restrict__ Bt,
    unsigned short* __restrict__ qb, unsigned short* __restrict__ Kimg,
    unsigned short* __restrict__ Vimg,
    const float* __restrict__ cosT, const float* __restrict__ sinT)
{
  __shared__ unsigned short sm[24576];  // 2x12288 staging; V-epilogue reuses [0,9216)
  const int bm = blockIdx.y * 64, bn0 = blockIdx.x;
  const int tid = threadIdx.x;
  const int w = tid >> 6, lane = tid & 63, l16 = lane & 15, quad = lane >> 4;
  const int mh = (w & 1) * 32, nh = (w >> 1) * 64;

  f32_4 acc[2][4];
#pragma unroll
  for (int mt = 0; mt < 2; ++mt)
#pragma unroll
    for (int nt = 0; nt < 4; ++nt) acc[mt][nt] = (f32_4){0.f, 0.f, 0.f, 0.f};

  G64DB_KLOOP(A, Bt);

  const int colbase = bn0 * 128;
  if (colbase < 1024) {            // ---- Q: rope + scale ----
#pragma unroll
    for (int mt = 0; mt < 2; ++mt)
#pragma unroll
      for (int r = 0; r < 4; ++r) {
        const int row = bm + mh + mt * 16 + quad * 4 + r;
        const int s = row & (S_LEN - 1);
#pragma unroll
        for (int nt = 0; nt < 4; ++nt) {
          const int col = colbase + nh + nt * 16 + l16;
          float val = acc[mt][nt][r];
          const float pv = __shfl_xor(val, 1);
          const int fi = (col & 63) >> 1;
          const float cc = cosT[s * 32 + fi], ss = sinT[s * 32 + fi];
          val = (l16 & 1) ? fmaf(pv, ss, val * cc) : fmaf(val, cc, -(pv * ss));
          qb[(size_t)row * 1024 + col] = ftob(val * QSCALE);
        }
      }
  } else if (colbase < 1280) {     // ---- K: rope -> swizzled image scatter ----
#pragma unroll
    for (int mt = 0; mt < 2; ++mt)
#pragma unroll
      for (int r = 0; r < 4; ++r) {
        const int row = bm + mh + mt * 16 + quad * 4 + r;
        const int s = row & (S_LEN - 1), bi = row >> 11;
        const int tile = s >> 6, key = s & 63;
#pragma unroll
        for (int nt = 0; nt < 4; ++nt) {
          const int col = colbase + nh + nt * 16 + l16;
          float val = acc[mt][nt][r];
          const float pv = __shfl_xor(val, 1);
          const int fi = (col & 63) >> 1;
          const float cc = cosT[s * 32 + fi], ss = sinT[s * 32 + fi];
          val = (l16 & 1) ? fmaf(pv, ss, val * cc) : fmaf(val, cc, -(pv * ss));
          const int gcol = col - 1024, g = gcol >> 6, d = gcol & 63;
          Kimg[(size_t)((bi * 4 + g) * 32 + tile) * 4096 + key * 64 +
               (((d >> 3) ^ (key & 7)) * 8) + (d & 7)] = ftob(val);
        }
      }
  } else {                         // ---- V: LDS transpose -> swizzled image ----
    const int bi = bm >> 11, t0 = (bm & 2047) >> 6;
    const int gp = (bn0 - 10) * 2;
    __syncthreads();               // staging reads done before sm reuse
    {
      // wave w covers group gp + (w>>1), keys mh..mh+31, d 0..63
      unsigned short* Ts = sm + (w >> 1) * 4608;   // [64 d][72]
#pragma unroll
      for (int mt = 0; mt < 2; ++mt)
#pragma unroll
        for (int nt = 0; nt < 4; ++nt) {
          const int keyb = mh + mt * 16 + quad * 4;  // 4 consecutive keys
          const int d = nt * 16 + l16;
          ushort4 pk;
#pragma unroll
          for (int r = 0; r < 4; ++r) ((unsigned short*)&pk)[r] = ftob(acc[mt][nt][r]);
          *(ushort4*)&Ts[d * 72 + keyb] = pk;
        }
    }
    __syncthreads();
#pragma unroll
    for (int it = 0; it < 4; ++it) {
      const int c = tid + it * 256;              // 1024 chunks: 2 imgs x 512
      const int img = c >> 9, cc = c & 511;
      const int d = cc >> 3, ch = cc & 7;
      const uint4 v = *(const uint4*)&sm[img * 4608 + d * 72 + ch * 8];
      *(uint4*)&Vimg[(size_t)((bi * 4 + gp + img) * 32 + t0) * 4096 + d * 64 +
                     ((ch ^ (d & 7)) * 8)] = v;
    }
  }
}

// ---------------------------------------------------------------------------
// Output GEMM: out[4096][1024] fp32 = attn @ wot^T. BM=64, BN=128, grid (8,64).
// ---------------------------------------------------------------------------
__global__ __launch_bounds__(256, 2) void gemm_wo(
    const unsigned short* __restrict__ A, const unsigned short* __restrict__ Bt,
    float* __restrict__ C)
{
  __shared__ unsigned short sm[24576];
  const int bm = blockIdx.y * 64, bn0 = blockIdx.x;
  const int tid = threadIdx.x;
  const int w = tid >> 6, lane = tid & 63, l16 = lane & 15, quad = lane >> 4;
  const int mh = (w & 1) * 32, nh = (w >> 1) * 64;

  f32_4 acc[2][4];
#pragma unroll
  for (int mt = 0; mt < 2; ++mt)
#pragma unroll
    for (int nt = 0; nt < 4; ++nt) acc[mt][nt] = (f32_4){0.f, 0.f, 0.f, 0.f};

  G64DB_KLOOP(A, Bt);

#pragma unroll
  for (int mt = 0; mt < 2; ++mt)
#pragma unroll
    for (int r = 0; r < 4; ++r) {
      const int row = bm + mh + mt * 16 + quad * 4 + r;
#pragma unroll
      for (int nt = 0; nt < 4; ++nt)
        C[(size_t)row * 1024 + bn0 * 128 + nh + nt * 16 + l16] = acc[mt][nt][r];
    }
}

// ---------------------------------------------------------------------------
// Flash attention v8: BARRIER-FREE. K/V fragments are read directly from the
// swizzled global images (XCD-pinned, 512 KB per (b,g) -> L2-resident); the
// image layout equals the old LDS layout, so frag addresses are unchanged.
// Removes both per-tile __syncthreads + the staging register block; the 4
// waves per block run fully independent (only Ps is per-wave-private LDS),
// so wave slip hides L2 latency and the exp2 VALU chain under MFMA.
// block = 32 q-rows x all 4 heads of one KV group; grid 512 (2/CU).
// O aliases qb: block reads rows [qbase,+32) cols [g*256,+256) at entry only,
// writes same region at exit; regions disjoint across blocks.
// ---------------------------------------------------------------------------
__global__ __launch_bounds__(256) void flash_attn_v8(
    const unsigned short* __restrict__ Q, const unsigned short* __restrict__ Kimg,
    const unsigned short* __restrict__ Vimg, unsigned short* __restrict__ O)
{
  __shared__ unsigned short Ps[4][2048];       // per-wave [32 q][64 key] swizzled
  const int id = blockIdx.x;
  const int gb = id & 7;                       // b*4+g -> XCD pin
  const int g = gb & 3, b = gb >> 2;
  const int j = id >> 3;                       // 0..63
  const int qc = (j < 32) ? (63 - j) : (j - 32);   // pair sums to 33 tiles
  const int tid = threadIdx.x;
  const int w = tid >> 6, lane = tid & 63, l16 = lane & 15, quad = lane >> 4;
  const int h = g * 4 + w;
  const int qbase = qc * 32;
  const int swz = l16 & 7;
  unsigned short* ps = Ps[w];

  // Q B-frags (register-resident): n = q = l16 (+16*qf), k = d = quad*8+j
  bf16_8 bq[2][2];
#pragma unroll
  for (int qf = 0; qf < 2; ++qf) {
    const unsigned short* qp =
        Q + ((size_t)(b * S_LEN + qbase + qf * 16 + l16)) * 1024 + h * 64;
    bq[qf][0] = *(const bf16_8*)(qp + quad * 8);
    bq[qf][1] = *(const bf16_8*)(qp + 32 + quad * 8);
  }

  f32_4 acc[2][4];
#pragma unroll
  for (int qf = 0; qf < 2; ++qf)
#pragma unroll
    for (int mt = 0; mt < 4; ++mt) acc[qf][mt] = (f32_4){0.f, 0.f, 0.f, 0.f};
  float l_part[2] = {0.f, 0.f};

  const unsigned short* kim = Kimg + (size_t)(gb * 32) * 4096;
  const unsigned short* vim = Vimg + (size_t)(gb * 32) * 4096;
  const int ntiles = (qc >> 1) + 1;

  for (int tile = 0; tile < ntiles; ++tile) {
    const unsigned short* kt = kim + (size_t)tile * 4096;
    const unsigned short* vt = vim + (size_t)tile * 4096;
    const bool diag = (tile == ntiles - 1);

    // ---- S^T = K Q^T (row=key, col=q), p = exp2(s), write Ps (b64) ----
#pragma unroll
    for (int mt = 0; mt < 4; ++mt) {
      const int krow = (mt * 16 + l16) * 64;
      const bf16_8 kf0 = *(const bf16_8*)&kt[krow + (quad ^ swz) * 8];
      const bf16_8 kf1 = *(const bf16_8*)&kt[krow + ((4 + quad) ^ swz) * 8];
#pragma unroll
      for (int qf = 0; qf < 2; ++qf) {
        f32_4 z = (f32_4){0.f, 0.f, 0.f, 0.f};
        __builtin_amdgcn_s_setprio(1);
        z = __builtin_amdgcn_mfma_f32_16x16x32_bf16(kf0, bq[qf][0], z, 0, 0, 0);
        z = __builtin_amdgcn_mfma_f32_16x16x32_bf16(kf1, bq[qf][1], z, 0, 0, 0);
        __builtin_amdgcn_s_setprio(0);
        ushort4 pk;
#pragma unroll
        for (int r = 0; r < 4; ++r) {
          float pv = __builtin_amdgcn_exp2f(z[r]);
          if (diag) {
            const int keyl = mt * 16 + quad * 4 + r;
            const int ql = (qc & 1) * 32 + qf * 16 + l16;
            pv = (keyl > ql) ? 0.f : pv;
          }
          l_part[qf] += pv;
          ((unsigned short*)&pk)[r] = ftob(pv);
        }
        // q-row qf*16+l16, keys mt*16+quad*4.. -> chunk 2mt+(quad>>1), swizzled
        *(ushort4*)&ps[(qf * 16 + l16) * 64 +
                       (((2 * mt + (quad >> 1)) ^ swz) * 8) + (quad & 1) * 4] = pk;
      }
    }
    // ---- P B-frags from Ps (per-wave private; in-wave lgkm ordering) ----
    bf16_8 pf[2][2];
#pragma unroll
    for (int qf = 0; qf < 2; ++qf) {
      const int prow = (qf * 16 + l16) * 64;
      pf[qf][0] = *(const bf16_8*)&ps[prow + ((quad ^ swz) * 8)];
      pf[qf][1] = *(const bf16_8*)&ps[prow + (((4 + quad) ^ swz) * 8)];
    }
    // ---- O^T += V^T @ P^T (V frags straight from L2 image) ----
    __builtin_amdgcn_s_setprio(1);
#pragma unroll
    for (int mt = 0; mt < 4; ++mt) {
      const int vrow = (mt * 16 + l16) * 64;
      const bf16_8 vf0 = *(const bf16_8*)&vt[vrow + (quad ^ swz) * 8];
      const bf16_8 vf1 = *(const bf16_8*)&vt[vrow + ((4 + quad) ^ swz) * 8];
#pragma unroll
      for (int qf = 0; qf < 2; ++qf) {
        acc[qf][mt] = __builtin_amdgcn_mfma_f32_16x16x32_bf16(vf0, pf[qf][0], acc[qf][mt], 0, 0, 0);
        acc[qf][mt] = __builtin_amdgcn_mfma_f32_16x16x32_bf16(vf1, pf[qf][1], acc[qf][mt], 0, 0, 0);
      }
    }
    __builtin_amdgcn_s_setprio(0);
  }

  // ---- finalize: l = sum over quads (keys partitioned by quad), write O^T ----
#pragma unroll
  for (int qf = 0; qf < 2; ++qf) {
    float l = l_part[qf];
    l += __shfl_xor(l, 16);
    l += __shfl_xor(l, 32);
    const float inv = 1.f / l;
    unsigned short* op =
        O + ((size_t)(b * S_LEN + qbase + qf * 16 + l16)) * 1024 + h * 64;
#pragma unroll
    for (int mt = 0; mt < 4; ++mt) {
      ushort4 ov;
#pragma unroll
      for (int r = 0; r < 4; ++r) ((unsigned short*)&ov)[r] = ftob(acc[qf][mt][r] * inv);
      *(ushort4*)&op[mt * 16 + quad * 4] = ov;
    }
  }
}

// ---------------------------------------------------------------------------
extern "C" void kernel_launch(void* const* d_in, const int* in_sizes, int n_in,
                              void* d_out, int out_size, void* d_ws, size_t ws_size,
                              hipStream_t stream)
{
  const float* x    = (const float*)d_in[0];
  const float* cosT = (const float*)d_in[1];
  const float* sinT = (const float*)d_in[2];
  const float* wq   = (const float*)d_in[4];
  const float* wk   = (const float*)d_in[5];
  const float* wv   = (const float*)d_in[6];
  const float* wo   = (const float*)d_in[7];
  float* out = (float*)d_out;

  char* ws = (char*)d_ws;
  const size_t MB = 1024 * 1024;
  unsigned short* xb    = (unsigned short*)(ws);             // 8 MB
  unsigned short* qb    = (unsigned short*)(ws + 8 * MB);    // 8 MB [4096][1024]
  unsigned short* wqkvt = (unsigned short*)(ws + 16 * MB);   // 3 MB [1536][1024]
  unsigned short* Kimg  = (unsigned short*)(ws + 19 * MB);   // 2 MB: 256 x 4096 (swizzled)
  unsigned short* Vimg  = (unsigned short*)(ws + 21 * MB);   // 2 MB: 256 x 4096 (swizzled)
  unsigned short* wot   = (unsigned short*)(ws + 23 * MB);   // 2 MB [1024][1024]
  // total ws use: 25 MB

  prep<<<3584, 256, 0, stream>>>(x, wq, wk, wv, wo, xb, wqkvt, wot);
  gemm_qkv<<<dim3(12, 64), 256, 0, stream>>>(xb, wqkvt, qb, Kimg, Vimg, cosT, sinT);
  flash_attn_v8<<<512, 256, 0, stream>>>(qb, Kimg, Vimg, qb);
  gemm_wo<<<dim3(8, 64), 256, 0, stream>>>(qb, wot, out);
}

// Round 4
// 173.651 us; speedup vs baseline: 1.1999x; 1.1999x over previous
//
#include <hip/hip_runtime.h>
#include <math.h>

#define S_LEN 2048
#define B_SZ 2

typedef __bf16 bf16_8 __attribute__((ext_vector_type(8)));
typedef float  f32_4  __attribute__((ext_vector_type(4)));

__device__ __forceinline__ unsigned short ftob(float f) {
  union { __bf16 h; unsigned short u; } cv;
  cv.h = (__bf16)f;              // fptrunc -> RNE
  return cv.u;
}

// async global->LDS, 16B per lane. LDS dest must be wave-uniform base + lane*16.
__device__ __forceinline__ void gll16(const unsigned short* g, unsigned short* l) {
  __builtin_amdgcn_global_load_lds(
      (const __attribute__((address_space(1))) unsigned int*)g,
      (__attribute__((address_space(3))) unsigned int*)l, 16, 0, 0);
}

// fold 1/sqrt(64) * log2(e) into Q at projection -> softmax in exp2 domain
#define QSCALE (0.125f * 1.44269504f)

// K/V tile images: dense 64x64 bf16 (4096 shorts = 8 KB), 16B-chunk XOR
// swizzle: element (row, col) at row*64 + ((col>>3) ^ (row&7))*8 + (col&7).
// K image rows = key, cols = d. V image rows = d, cols = key.
// Image layout == LDS layout, so staging is a straight 8 KB memcpy ->
// global_load_lds DMA (no reg roundtrip, no ds_write instructions).

// ---------------------------------------------------------------------------
// 32x32 transpose+convert tile helper: W[K=1024][N] fp32 -> Wt[N][1024] bf16.
// ---------------------------------------------------------------------------
__device__ __forceinline__ void tr_tile(const float* __restrict__ W,
                                        unsigned short* __restrict__ Wt,
                                        int N, int bx, int by, float (*T)[33])
{
  const int k0 = by * 32, n0 = bx * 32;
  const int r = threadIdx.x >> 3, c4 = (threadIdx.x & 7) * 4;
  const float4 v = *(const float4*)&W[(size_t)(k0 + r) * N + n0 + c4];
  T[r][c4 + 0] = v.x; T[r][c4 + 1] = v.y;
  T[r][c4 + 2] = v.z; T[r][c4 + 3] = v.w;
  __syncthreads();
  ushort4 o;
  o.x = ftob(T[c4 + 0][r]); o.y = ftob(T[c4 + 1][r]);
  o.z = ftob(T[c4 + 2][r]); o.w = ftob(T[c4 + 3][r]);
  *(ushort4*)&Wt[(size_t)(n0 + r) * 1024 + k0 + c4] = o;
}

// ---------------------------------------------------------------------------
// prep: [0,1024) wq->wqkvt | [1024,1280) wk | [1280,1536) wv |
//       [1536,2560) wo->wot | [2560,3584) x fp32->bf16
// ---------------------------------------------------------------------------
__global__ __launch_bounds__(256) void prep(
    const float* __restrict__ x, const float* __restrict__ wq,
    const float* __restrict__ wk, const float* __restrict__ wv,
    const float* __restrict__ wo,
    unsigned short* __restrict__ xb, unsigned short* __restrict__ wqkvt,
    unsigned short* __restrict__ wot)
{
  __shared__ float T[32][33];
  const int idx = blockIdx.x;
  if (idx < 1024) {
    tr_tile(wq, wqkvt, 1024, idx & 31, idx >> 5, T);
  } else if (idx < 1280) {
    const int i = idx - 1024;
    tr_tile(wk, wqkvt + 1024 * 1024, 256, i & 7, i >> 3, T);
  } else if (idx < 1536) {
    const int i = idx - 1280;
    tr_tile(wv, wqkvt + 1280 * 1024, 256, i & 7, i >> 3, T);
  } else if (idx < 2560) {
    const int i = idx - 1536;
    tr_tile(wo, wot, 1024, i & 31, i >> 5, T);
  } else {
    const int i = idx - 2560;
#pragma unroll
    for (int j = 0; j < 4; ++j) {
      const int id = i * 1024 + (int)threadIdx.x + j * 256;
      const float4 v = ((const float4*)x)[id];
      ushort4 o;
      o.x = ftob(v.x); o.y = ftob(v.y); o.z = ftob(v.z); o.w = ftob(v.w);
      ((ushort4*)xb)[id] = o;
    }
  }
}

// ---------------------------------------------------------------------------
// 64x128 GEMM core, 2-phase: BK=64 (stored as two BK=32 panels, preserving the
// m97 bank layout), double-buffered LDS (2 x 24 KB), global_load_lds w16,
// ONE barrier per K-step. STAGE(next) is issued before ds_read+MFMA of the
// current buffer, so the 6 in-flight loads drain under compute; the barrier's
// vmcnt(0) then covers the prefetch. 16 steps, 17 barriers total (vs 64).
// Buffer layout (shorts, per 12288-buf): [0,2048) A k0 | [2048,4096) A k1 |
// [4096,8192) B k0 (128 rows) | [8192,12288) B k1.
// ---------------------------------------------------------------------------
#define G64DB_STAGE(A_, B_, bo_, k0_)                                           \
  do {                                                                          \
    const int r = tid >> 2, o8 = (tid & 3) * 8;                                 \
    gll16(&A_[(size_t)(bm + r) * 1024 + (k0_) + o8], &sm[(bo_) + tid * 8]);     \
    gll16(&A_[(size_t)(bm + r) * 1024 + (k0_) + 32 + o8],                       \
          &sm[(bo_) + 2048 + tid * 8]);                                         \
    gll16(&B_[(size_t)(bn0 * 128 + r) * 1024 + (k0_) + o8],                     \
          &sm[(bo_) + 4096 + tid * 8]);                                         \
    gll16(&B_[(size_t)(bn0 * 128 + r + 64) * 1024 + (k0_) + o8],                \
          &sm[(bo_) + 6144 + tid * 8]);                                         \
    gll16(&B_[(size_t)(bn0 * 128 + r) * 1024 + (k0_) + 32 + o8],                \
          &sm[(bo_) + 8192 + tid * 8]);                                         \
    gll16(&B_[(size_t)(bn0 * 128 + r + 64) * 1024 + (k0_) + 32 + o8],           \
          &sm[(bo_) + 10240 + tid * 8]);                                        \
  } while (0)

#define G64DB_KLOOP(A_, B_)                                                     \
  G64DB_STAGE(A_, B_, 0, 0);                                                    \
  __syncthreads();                                                              \
  for (int s = 0; s < 16; ++s) {                                                \
    const int bo = (s & 1) * 12288;                                             \
    if (s < 15) G64DB_STAGE(A_, B_, bo ^ 12288, (s + 1) * 64);                  \
    bf16_8 af[2][2], bf[2][4];                                                  \
    _Pragma("unroll")                                                           \
    for (int ks = 0; ks < 2; ++ks) {                                            \
      _Pragma("unroll")                                                         \
      for (int mt = 0; mt < 2; ++mt)                                            \
        af[ks][mt] = *(const bf16_8*)&sm[bo + ks * 2048 +                       \
                                         (mh + mt * 16 + l16) * 32 + quad * 8]; \
      _Pragma("unroll")                                                         \
      for (int nt = 0; nt < 4; ++nt)                                            \
        bf[ks][nt] = *(const bf16_8*)&sm[bo + 4096 + ks * 4096 +                \
                                         (nh + nt * 16 + l16) * 32 + quad * 8]; \
    }                                                                           \
    _Pragma("unroll")                                                           \
    for (int ks = 0; ks < 2; ++ks)                                              \
      _Pragma("unroll")                                                         \
      for (int mt = 0; mt < 2; ++mt)                                            \
        _Pragma("unroll")                                                       \
        for (int nt = 0; nt < 4; ++nt)                                          \
          acc[mt][nt] = __builtin_amdgcn_mfma_f32_16x16x32_bf16(                \
              af[ks][mt], bf[ks][nt], acc[mt][nt], 0, 0, 0);                    \
    __syncthreads();                                                            \
  }

// ---------------------------------------------------------------------------
// Fused QKV GEMM: [4096][1536] = xb @ wqkvt^T. BM=64, BN=128, grid (12,64).
// Epilogue by column block: bn0 0..7 Q rope+scale -> qb; 8..9 K rope -> Kimg
// (swizzled); 10..11 V -> LDS transpose -> Vimg (swizzled, b128 stores).
// ---------------------------------------------------------------------------
__global__ __launch_bounds__(256, 3) void gemm_qkv(
    const unsigned short* __restrict__ A, const unsigned short* __restrict__ Bt,
    unsigned short* __restrict__ qb, unsigned short* __restrict__ Kimg,
    unsigned short* __restrict__ Vimg,
    const float* __restrict__ cosT, const float* __restrict__ sinT)
{
  __shared__ unsigned short sm[24576];  // 2x12288 staging; V-epilogue reuses [0,9216)
  const int bm = blockIdx.y * 64, bn0 = blockIdx.x;
  const int tid = threadIdx.x;
  const int w = tid >> 6, lane = tid & 63, l16 = lane & 15, quad = lane >> 4;
  const int mh = (w & 1) * 32, nh = (w >> 1) * 64;

  f32_4 acc[2][4];
#pragma unroll
  for (int mt = 0; mt < 2; ++mt)
#pragma unroll
    for (int nt = 0; nt < 4; ++nt) acc[mt][nt] = (f32_4){0.f, 0.f, 0.f, 0.f};

  G64DB_KLOOP(A, Bt);

  const int colbase = bn0 * 128;
  if (colbase < 1024) {            // ---- Q: rope + scale ----
#pragma unroll
    for (int mt = 0; mt < 2; ++mt)
#pragma unroll
      for (int r = 0; r < 4; ++r) {
        const int row = bm + mh + mt * 16 + quad * 4 + r;
        const int s = row & (S_LEN - 1);
#pragma unroll
        for (int nt = 0; nt < 4; ++nt) {
          const int col = colbase + nh + nt * 16 + l16;
          float val = acc[mt][nt][r];
          const float pv = __shfl_xor(val, 1);
          const int fi = (col & 63) >> 1;
          const float cc = cosT[s * 32 + fi], ss = sinT[s * 32 + fi];
          val = (l16 & 1) ? fmaf(pv, ss, val * cc) : fmaf(val, cc, -(pv * ss));
          qb[(size_t)row * 1024 + col] = ftob(val * QSCALE);
        }
      }
  } else if (colbase < 1280) {     // ---- K: rope -> swizzled image scatter ----
#pragma unroll
    for (int mt = 0; mt < 2; ++mt)
#pragma unroll
      for (int r = 0; r < 4; ++r) {
        const int row = bm + mh + mt * 16 + quad * 4 + r;
        const int s = row & (S_LEN - 1), bi = row >> 11;
        const int tile = s >> 6, key = s & 63;
#pragma unroll
        for (int nt = 0; nt < 4; ++nt) {
          const int col = colbase + nh + nt * 16 + l16;
          float val = acc[mt][nt][r];
          const float pv = __shfl_xor(val, 1);
          const int fi = (col & 63) >> 1;
          const float cc = cosT[s * 32 + fi], ss = sinT[s * 32 + fi];
          val = (l16 & 1) ? fmaf(pv, ss, val * cc) : fmaf(val, cc, -(pv * ss));
          const int gcol = col - 1024, g = gcol >> 6, d = gcol & 63;
          Kimg[(size_t)((bi * 4 + g) * 32 + tile) * 4096 + key * 64 +
               (((d >> 3) ^ (key & 7)) * 8) + (d & 7)] = ftob(val);
        }
      }
  } else {                         // ---- V: LDS transpose -> swizzled image ----
    const int bi = bm >> 11, t0 = (bm & 2047) >> 6;
    const int gp = (bn0 - 10) * 2;
    __syncthreads();               // staging reads done before sm reuse
    {
      // wave w covers group gp + (w>>1), keys mh..mh+31, d 0..63
      unsigned short* Ts = sm + (w >> 1) * 4608;   // [64 d][72]
#pragma unroll
      for (int mt = 0; mt < 2; ++mt)
#pragma unroll
        for (int nt = 0; nt < 4; ++nt) {
          const int keyb = mh + mt * 16 + quad * 4;  // 4 consecutive keys
          const int d = nt * 16 + l16;
          ushort4 pk;
#pragma unroll
          for (int r = 0; r < 4; ++r) ((unsigned short*)&pk)[r] = ftob(acc[mt][nt][r]);
          *(ushort4*)&Ts[d * 72 + keyb] = pk;
        }
    }
    __syncthreads();
#pragma unroll
    for (int it = 0; it < 4; ++it) {
      const int c = tid + it * 256;              // 1024 chunks: 2 imgs x 512
      const int img = c >> 9, cc = c & 511;
      const int d = cc >> 3, ch = cc & 7;
      const uint4 v = *(const uint4*)&sm[img * 4608 + d * 72 + ch * 8];
      *(uint4*)&Vimg[(size_t)((bi * 4 + gp + img) * 32 + t0) * 4096 + d * 64 +
                     ((ch ^ (d & 7)) * 8)] = v;
    }
  }
}

// ---------------------------------------------------------------------------
// Output GEMM: out[4096][1024] fp32 = attn @ wot^T. BM=64, BN=128, grid (8,64).
// ---------------------------------------------------------------------------
__global__ __launch_bounds__(256, 2) void gemm_wo(
    const unsigned short* __restrict__ A, const unsigned short* __restrict__ Bt,
    float* __restrict__ C)
{
  __shared__ unsigned short sm[24576];
  const int bm = blockIdx.y * 64, bn0 = blockIdx.x;
  const int tid = threadIdx.x;
  const int w = tid >> 6, lane = tid & 63, l16 = lane & 15, quad = lane >> 4;
  const int mh = (w & 1) * 32, nh = (w >> 1) * 64;

  f32_4 acc[2][4];
#pragma unroll
  for (int mt = 0; mt < 2; ++mt)
#pragma unroll
    for (int nt = 0; nt < 4; ++nt) acc[mt][nt] = (f32_4){0.f, 0.f, 0.f, 0.f};

  G64DB_KLOOP(A, Bt);

#pragma unroll
  for (int mt = 0; mt < 2; ++mt)
#pragma unroll
    for (int r = 0; r < 4; ++r) {
      const int row = bm + mh + mt * 16 + quad * 4 + r;
#pragma unroll
      for (int nt = 0; nt < 4; ++nt)
        C[(size_t)row * 1024 + bn0 * 128 + nh + nt * 16 + l16] = acc[mt][nt][r];
    }
}

// ---------------------------------------------------------------------------
// Flash attention v9: v7 structure (LDS-staged K/V — v8 proved direct-L2 reads
// are latency-bound at 2 waves/SIMD) but staging via global_load_lds DMA into
// DOUBLE-BUFFERED Ks/Vs: no reg roundtrip, no ds_write instructions, ONE
// barrier per tile, prefetch issued right after the barrier so it has the
// whole compute phase to drain before the next barrier's vmcnt(0).
// block = 32 q-rows x all 4 heads of one KV group; grid 512 (2/CU).
// gb = id&7 pins (b,g) to one XCD; co-resident pair sums to 33 tiles.
// O aliases qb: block reads rows [qbase,+32) cols [g*256,+256) at entry only,
// writes same region at exit; regions disjoint across blocks.
// ---------------------------------------------------------------------------
__global__ __launch_bounds__(256) void flash_attn_v9(
    const unsigned short* __restrict__ Q, const unsigned short* __restrict__ Kimg,
    const unsigned short* __restrict__ Vimg, unsigned short* __restrict__ O)
{
  __shared__ unsigned short Ks[2][4096];       // [key][d] swizzled, dbuf
  __shared__ unsigned short Vs[2][4096];       // [d][key] swizzled, dbuf
  __shared__ unsigned short Ps[4][2048];       // per-wave [32 q][64 key] swizzled
  const int id = blockIdx.x;
  const int gb = id & 7;                       // b*4+g -> XCD pin
  const int g = gb & 3, b = gb >> 2;
  const int j = id >> 3;                       // 0..63
  const int qc = (j < 32) ? (63 - j) : (j - 32);   // pair sums to 33 tiles
  const int tid = threadIdx.x;
  const int w = tid >> 6, lane = tid & 63, l16 = lane & 15, quad = lane >> 4;
  const int h = g * 4 + w;
  const int qbase = qc * 32;
  const int swz = l16 & 7;
  unsigned short* ps = Ps[w];

  // Q B-frags (register-resident): n = q = l16 (+16*qf), k = d = quad*8+j
  bf16_8 bq[2][2];
#pragma unroll
  for (int qf = 0; qf < 2; ++qf) {
    const unsigned short* qp =
        Q + ((size_t)(b * S_LEN + qbase + qf * 16 + l16)) * 1024 + h * 64;
    bq[qf][0] = *(const bf16_8*)(qp + quad * 8);
    bq[qf][1] = *(const bf16_8*)(qp + 32 + quad * 8);
  }

  f32_4 acc[2][4];
#pragma unroll
  for (int qf = 0; qf < 2; ++qf)
#pragma unroll
    for (int mt = 0; mt < 4; ++mt) acc[qf][mt] = (f32_4){0.f, 0.f, 0.f, 0.f};
  float l_part[2] = {0.f, 0.f};

  const unsigned short* kim = Kimg + (size_t)(gb * 32) * 4096;
  const unsigned short* vim = Vimg + (size_t)(gb * 32) * 4096;
  const int ntiles = (qc >> 1) + 1;

  // DMA staging: 8 KB per image; thread owns 16B chunks tid, tid+256 of each
#define FA_STAGE(t, c)                                                          \
  do {                                                                          \
    const unsigned short* kp = kim + (size_t)(t) * 4096;                        \
    const unsigned short* vp = vim + (size_t)(t) * 4096;                        \
    gll16(kp + tid * 8, &Ks[c][tid * 8]);                                       \
    gll16(kp + (tid + 256) * 8, &Ks[c][(tid + 256) * 8]);                       \
    gll16(vp + tid * 8, &Vs[c][tid * 8]);                                       \
    gll16(vp + (tid + 256) * 8, &Vs[c][(tid + 256) * 8]);                       \
  } while (0)

  FA_STAGE(0, 0);
  for (int tile = 0; tile < ntiles; ++tile) {
    const int c = tile & 1;
    __syncthreads();                           // drains own vmcnt -> buf c ready
    if (tile + 1 < ntiles) FA_STAGE(tile + 1, c ^ 1);  // prev readers of c^1 done

    const bool diag = (tile == ntiles - 1);
    const unsigned short* ks = Ks[c];
    const unsigned short* vs = Vs[c];
    // ---- S^T = K Q^T (row=key, col=q), p = exp2(s), write Ps (b64) ----
#pragma unroll
    for (int mt = 0; mt < 4; ++mt) {
      const int krow = (mt * 16 + l16) * 64;
      const bf16_8 kf0 = *(const bf16_8*)&ks[krow + (quad ^ swz) * 8];
      const bf16_8 kf1 = *(const bf16_8*)&ks[krow + ((4 + quad) ^ swz) * 8];
#pragma unroll
      for (int qf = 0; qf < 2; ++qf) {
        f32_4 z = (f32_4){0.f, 0.f, 0.f, 0.f};
        __builtin_amdgcn_s_setprio(1);
        z = __builtin_amdgcn_mfma_f32_16x16x32_bf16(kf0, bq[qf][0], z, 0, 0, 0);
        z = __builtin_amdgcn_mfma_f32_16x16x32_bf16(kf1, bq[qf][1], z, 0, 0, 0);
        __builtin_amdgcn_s_setprio(0);
        ushort4 pk;
#pragma unroll
        for (int r = 0; r < 4; ++r) {
          float pv = __builtin_amdgcn_exp2f(z[r]);
          if (diag) {
            const int keyl = mt * 16 + quad * 4 + r;
            const int ql = (qc & 1) * 32 + qf * 16 + l16;
            pv = (keyl > ql) ? 0.f : pv;
          }
          l_part[qf] += pv;
          ((unsigned short*)&pk)[r] = ftob(pv);
        }
        // q-row qf*16+l16, keys mt*16+quad*4.. -> chunk 2mt+(quad>>1), swizzled
        *(ushort4*)&ps[(qf * 16 + l16) * 64 +
                       (((2 * mt + (quad >> 1)) ^ swz) * 8) + (quad & 1) * 4] = pk;
      }
    }
    // ---- P B-frags from Ps (per-wave private; in-wave lgkm ordering) ----
    bf16_8 pf[2][2];
#pragma unroll
    for (int qf = 0; qf < 2; ++qf) {
      const int prow = (qf * 16 + l16) * 64;
      pf[qf][0] = *(const bf16_8*)&ps[prow + ((quad ^ swz) * 8)];
      pf[qf][1] = *(const bf16_8*)&ps[prow + (((4 + quad) ^ swz) * 8)];
    }
    // ---- O^T += V^T @ P^T ----
    __builtin_amdgcn_s_setprio(1);
#pragma unroll
    for (int mt = 0; mt < 4; ++mt) {
      const int vrow = (mt * 16 + l16) * 64;
      const bf16_8 vf0 = *(const bf16_8*)&vs[vrow + (quad ^ swz) * 8];
      const bf16_8 vf1 = *(const bf16_8*)&vs[vrow + ((4 + quad) ^ swz) * 8];
#pragma unroll
      for (int qf = 0; qf < 2; ++qf) {
        acc[qf][mt] = __builtin_amdgcn_mfma_f32_16x16x32_bf16(vf0, pf[qf][0], acc[qf][mt], 0, 0, 0);
        acc[qf][mt] = __builtin_amdgcn_mfma_f32_16x16x32_bf16(vf1, pf[qf][1], acc[qf][mt], 0, 0, 0);
      }
    }
    __builtin_amdgcn_s_setprio(0);
  }

  // ---- finalize: l = sum over quads (keys partitioned by quad), write O^T ----
#pragma unroll
  for (int qf = 0; qf < 2; ++qf) {
    float l = l_part[qf];
    l += __shfl_xor(l, 16);
    l += __shfl_xor(l, 32);
    const float inv = 1.f / l;
    unsigned short* op =
        O + ((size_t)(b * S_LEN + qbase + qf * 16 + l16)) * 1024 + h * 64;
#pragma unroll
    for (int mt = 0; mt < 4; ++mt) {
      ushort4 ov;
#pragma unroll
      for (int r = 0; r < 4; ++r) ((unsigned short*)&ov)[r] = ftob(acc[qf][mt][r] * inv);
      *(ushort4*)&op[mt * 16 + quad * 4] = ov;
    }
  }
}

// ---------------------------------------------------------------------------
extern "C" void kernel_launch(void* const* d_in, const int* in_sizes, int n_in,
                              void* d_out, int out_size, void* d_ws, size_t ws_size,
                              hipStream_t stream)
{
  const float* x    = (const float*)d_in[0];
  const float* cosT = (const float*)d_in[1];
  const float* sinT = (const float*)d_in[2];
  const float* wq   = (const float*)d_in[4];
  const float* wk   = (const float*)d_in[5];
  const float* wv   = (const float*)d_in[6];
  const float* wo   = (const float*)d_in[7];
  float* out = (float*)d_out;

  char* ws = (char*)d_ws;
  const size_t MB = 1024 * 1024;
  unsigned short* xb    = (unsigned short*)(ws);             // 8 MB
  unsigned short* qb    = (unsigned short*)(ws + 8 * MB);    // 8 MB [4096][1024]
  unsigned short* wqkvt = (unsigned short*)(ws + 16 * MB);   // 3 MB [1536][1024]
  unsigned short* Kimg  = (unsigned short*)(ws + 19 * MB);   // 2 MB: 256 x 4096 (swizzled)
  unsigned short* Vimg  = (unsigned short*)(ws + 21 * MB);   // 2 MB: 256 x 4096 (swizzled)
  unsigned short* wot   = (unsigned short*)(ws + 23 * MB);   // 2 MB [1024][1024]
  // total ws use: 25 MB

  prep<<<3584, 256, 0, stream>>>(x, wq, wk, wv, wo, xb, wqkvt, wot);
  gemm_qkv<<<dim3(12, 64), 256, 0, stream>>>(xb, wqkvt, qb, Kimg, Vimg, cosT, sinT);
  flash_attn_v9<<<512, 256, 0, stream>>>(qb, Kimg, Vimg, qb);
  gemm_wo<<<dim3(8, 64), 256, 0, stream>>>(qb, wot, out);
}

// Round 5
// 163.962 us; speedup vs baseline: 1.2708x; 1.0591x over previous
//
#include <hip/hip_runtime.h>
#include <math.h>

#define S_LEN 2048
#define B_SZ 2

typedef __bf16 bf16_8 __attribute__((ext_vector_type(8)));
typedef float  f32_4  __attribute__((ext_vector_type(4)));

__device__ __forceinline__ unsigned short ftob(float f) {
  union { __bf16 h; unsigned short u; } cv;
  cv.h = (__bf16)f;              // fptrunc -> RNE
  return cv.u;
}

// async global->LDS, 16B per lane. LDS dest must be wave-uniform base + lane*16.
__device__ __forceinline__ void gll16(const unsigned short* g, unsigned short* l) {
  __builtin_amdgcn_global_load_lds(
      (const __attribute__((address_space(1))) unsigned int*)g,
      (__attribute__((address_space(3))) unsigned int*)l, 16, 0, 0);
}

// fold 1/sqrt(64) * log2(e) into Q at projection -> softmax in exp2 domain
#define QSCALE (0.125f * 1.44269504f)

// K/V tile images: dense 64x64 bf16 (4096 shorts = 8 KB), 16B-chunk XOR
// swizzle: element (row, col) at row*64 + ((col>>3) ^ (row&7))*8 + (col&7).
// K image rows = key, cols = d. V image rows = d, cols = key.
// Image layout == LDS layout -> staging is a straight memcpy via
// global_load_lds DMA (no reg roundtrip, no ds_write instructions).

// ---------------------------------------------------------------------------
// 32x32 transpose+convert tile helper: W[K=1024][N] fp32 -> Wt[N][1024] bf16.
// ---------------------------------------------------------------------------
__device__ __forceinline__ void tr_tile(const float* __restrict__ W,
                                        unsigned short* __restrict__ Wt,
                                        int N, int bx, int by, float (*T)[33])
{
  const int k0 = by * 32, n0 = bx * 32;
  const int r = threadIdx.x >> 3, c4 = (threadIdx.x & 7) * 4;
  const float4 v = *(const float4*)&W[(size_t)(k0 + r) * N + n0 + c4];
  T[r][c4 + 0] = v.x; T[r][c4 + 1] = v.y;
  T[r][c4 + 2] = v.z; T[r][c4 + 3] = v.w;
  __syncthreads();
  ushort4 o;
  o.x = ftob(T[c4 + 0][r]); o.y = ftob(T[c4 + 1][r]);
  o.z = ftob(T[c4 + 2][r]); o.w = ftob(T[c4 + 3][r]);
  *(ushort4*)&Wt[(size_t)(n0 + r) * 1024 + k0 + c4] = o;
}

// ---------------------------------------------------------------------------
// prep: [0,1024) wq->wqkvt | [1024,1280) wk | [1280,1536) wv |
//       [1536,2560) wo->wot | [2560,3584) x fp32->bf16
// ---------------------------------------------------------------------------
__global__ __launch_bounds__(256) void prep(
    const float* __restrict__ x, const float* __restrict__ wq,
    const float* __restrict__ wk, const float* __restrict__ wv,
    const float* __restrict__ wo,
    unsigned short* __restrict__ xb, unsigned short* __restrict__ wqkvt,
    unsigned short* __restrict__ wot)
{
  __shared__ float T[32][33];
  const int idx = blockIdx.x;
  if (idx < 1024) {
    tr_tile(wq, wqkvt, 1024, idx & 31, idx >> 5, T);
  } else if (idx < 1280) {
    const int i = idx - 1024;
    tr_tile(wk, wqkvt + 1024 * 1024, 256, i & 7, i >> 3, T);
  } else if (idx < 1536) {
    const int i = idx - 1280;
    tr_tile(wv, wqkvt + 1280 * 1024, 256, i & 7, i >> 3, T);
  } else if (idx < 2560) {
    const int i = idx - 1536;
    tr_tile(wo, wot, 1024, i & 31, i >> 5, T);
  } else {
    const int i = idx - 2560;
#pragma unroll
    for (int j = 0; j < 4; ++j) {
      const int id = i * 1024 + (int)threadIdx.x + j * 256;
      const float4 v = ((const float4*)x)[id];
      ushort4 o;
      o.x = ftob(v.x); o.y = ftob(v.y); o.z = ftob(v.z); o.w = ftob(v.w);
      ((ushort4*)xb)[id] = o;
    }
  }
}

// ---------------------------------------------------------------------------
// 64x128 GEMM core, 2-phase: BK=64 (stored as two BK=32 panels, preserving the
// m97 bank layout), double-buffered LDS (2 x 24 KB), global_load_lds w16,
// ONE barrier per K-step. STAGE(next) is issued before ds_read+MFMA of the
// current buffer, so the 6 in-flight loads drain under compute.
// ---------------------------------------------------------------------------
#define G64DB_STAGE(A_, B_, bo_, k0_)                                           \
  do {                                                                          \
    const int r = tid >> 2, o8 = (tid & 3) * 8;                                 \
    gll16(&A_[(size_t)(bm + r) * 1024 + (k0_) + o8], &sm[(bo_) + tid * 8]);     \
    gll16(&A_[(size_t)(bm + r) * 1024 + (k0_) + 32 + o8],                       \
          &sm[(bo_) + 2048 + tid * 8]);                                         \
    gll16(&B_[(size_t)(bn0 * 128 + r) * 1024 + (k0_) + o8],                     \
          &sm[(bo_) + 4096 + tid * 8]);                                         \
    gll16(&B_[(size_t)(bn0 * 128 + r + 64) * 1024 + (k0_) + o8],                \
          &sm[(bo_) + 6144 + tid * 8]);                                         \
    gll16(&B_[(size_t)(bn0 * 128 + r) * 1024 + (k0_) + 32 + o8],                \
          &sm[(bo_) + 8192 + tid * 8]);                                         \
    gll16(&B_[(size_t)(bn0 * 128 + r + 64) * 1024 + (k0_) + 32 + o8],           \
          &sm[(bo_) + 10240 + tid * 8]);                                        \
  } while (0)

#define G64DB_KLOOP(A_, B_)                                                     \
  G64DB_STAGE(A_, B_, 0, 0);                                                    \
  __syncthreads();                                                              \
  for (int s = 0; s < 16; ++s) {                                                \
    const int bo = (s & 1) * 12288;                                             \
    if (s < 15) G64DB_STAGE(A_, B_, bo ^ 12288, (s + 1) * 64);                  \
    bf16_8 af[2][2], bf[2][4];                                                  \
    _Pragma("unroll")                                                           \
    for (int ks = 0; ks < 2; ++ks) {                                            \
      _Pragma("unroll")                                                         \
      for (int mt = 0; mt < 2; ++mt)                                            \
        af[ks][mt] = *(const bf16_8*)&sm[bo + ks * 2048 +                       \
                                         (mh + mt * 16 + l16) * 32 + quad * 8]; \
      _Pragma("unroll")                                                         \
      for (int nt = 0; nt < 4; ++nt)                                            \
        bf[ks][nt] = *(const bf16_8*)&sm[bo + 4096 + ks * 4096 +                \
                                         (nh + nt * 16 + l16) * 32 + quad * 8]; \
    }                                                                           \
    _Pragma("unroll")                                                           \
    for (int ks = 0; ks < 2; ++ks)                                              \
      _Pragma("unroll")                                                         \
      for (int mt = 0; mt < 2; ++mt)                                            \
        _Pragma("unroll")                                                       \
        for (int nt = 0; nt < 4; ++nt)                                          \
          acc[mt][nt] = __builtin_amdgcn_mfma_f32_16x16x32_bf16(                \
              af[ks][mt], bf[ks][nt], acc[mt][nt], 0, 0, 0);                    \
    __syncthreads();                                                            \
  }

// ---------------------------------------------------------------------------
// Fused QKV GEMM: [4096][1536] = xb @ wqkvt^T. BM=64, BN=128, grid (12,64).
// Epilogue by column block: bn0 0..7 Q rope+scale -> qb; 8..9 K rope -> Kimg
// (swizzled); 10..11 V -> LDS transpose -> Vimg (swizzled, b128 stores).
// ---------------------------------------------------------------------------
__global__ __launch_bounds__(256, 3) void gemm_qkv(
    const unsigned short* __restrict__ A, const unsigned short* __restrict__ Bt,
    unsigned short* __restrict__ qb, unsigned short* __restrict__ Kimg,
    unsigned short* __restrict__ Vimg,
    const float* __restrict__ cosT, const float* __restrict__ sinT)
{
  __shared__ unsigned short sm[24576];  // 2x12288 staging; V-epilogue reuses [0,9216)
  const int bm = blockIdx.y * 64, bn0 = blockIdx.x;
  const int tid = threadIdx.x;
  const int w = tid >> 6, lane = tid & 63, l16 = lane & 15, quad = lane >> 4;
  const int mh = (w & 1) * 32, nh = (w >> 1) * 64;

  f32_4 acc[2][4];
#pragma unroll
  for (int mt = 0; mt < 2; ++mt)
#pragma unroll
    for (int nt = 0; nt < 4; ++nt) acc[mt][nt] = (f32_4){0.f, 0.f, 0.f, 0.f};

  G64DB_KLOOP(A, Bt);

  const int colbase = bn0 * 128;
  if (colbase < 1024) {            // ---- Q: rope + scale ----
#pragma unroll
    for (int mt = 0; mt < 2; ++mt)
#pragma unroll
      for (int r = 0; r < 4; ++r) {
        const int row = bm + mh + mt * 16 + quad * 4 + r;
        const int s = row & (S_LEN - 1);
#pragma unroll
        for (int nt = 0; nt < 4; ++nt) {
          const int col = colbase + nh + nt * 16 + l16;
          float val = acc[mt][nt][r];
          const float pv = __shfl_xor(val, 1);
          const int fi = (col & 63) >> 1;
          const float cc = cosT[s * 32 + fi], ss = sinT[s * 32 + fi];
          val = (l16 & 1) ? fmaf(pv, ss, val * cc) : fmaf(val, cc, -(pv * ss));
          qb[(size_t)row * 1024 + col] = ftob(val * QSCALE);
        }
      }
  } else if (colbase < 1280) {     // ---- K: rope -> swizzled image scatter ----
#pragma unroll
    for (int mt = 0; mt < 2; ++mt)
#pragma unroll
      for (int r = 0; r < 4; ++r) {
        const int row = bm + mh + mt * 16 + quad * 4 + r;
        const int s = row & (S_LEN - 1), bi = row >> 11;
        const int tile = s >> 6, key = s & 63;
#pragma unroll
        for (int nt = 0; nt < 4; ++nt) {
          const int col = colbase + nh + nt * 16 + l16;
          float val = acc[mt][nt][r];
          const float pv = __shfl_xor(val, 1);
          const int fi = (col & 63) >> 1;
          const float cc = cosT[s * 32 + fi], ss = sinT[s * 32 + fi];
          val = (l16 & 1) ? fmaf(pv, ss, val * cc) : fmaf(val, cc, -(pv * ss));
          const int gcol = col - 1024, g = gcol >> 6, d = gcol & 63;
          Kimg[(size_t)((bi * 4 + g) * 32 + tile) * 4096 + key * 64 +
               (((d >> 3) ^ (key & 7)) * 8) + (d & 7)] = ftob(val);
        }
      }
  } else {                         // ---- V: LDS transpose -> swizzled image ----
    const int bi = bm >> 11, t0 = (bm & 2047) >> 6;
    const int gp = (bn0 - 10) * 2;
    __syncthreads();               // staging reads done before sm reuse
    {
      // wave w covers group gp + (w>>1), keys mh..mh+31, d 0..63
      unsigned short* Ts = sm + (w >> 1) * 4608;   // [64 d][72]
#pragma unroll
      for (int mt = 0; mt < 2; ++mt)
#pragma unroll
        for (int nt = 0; nt < 4; ++nt) {
          const int keyb = mh + mt * 16 + quad * 4;  // 4 consecutive keys
          const int d = nt * 16 + l16;
          ushort4 pk;
#pragma unroll
          for (int r = 0; r < 4; ++r) ((unsigned short*)&pk)[r] = ftob(acc[mt][nt][r]);
          *(ushort4*)&Ts[d * 72 + keyb] = pk;
        }
    }
    __syncthreads();
#pragma unroll
    for (int it = 0; it < 4; ++it) {
      const int c = tid + it * 256;              // 1024 chunks: 2 imgs x 512
      const int img = c >> 9, cc = c & 511;
      const int d = cc >> 3, ch = cc & 7;
      const uint4 v = *(const uint4*)&sm[img * 4608 + d * 72 + ch * 8];
      *(uint4*)&Vimg[(size_t)((bi * 4 + gp + img) * 32 + t0) * 4096 + d * 64 +
                     ((ch ^ (d & 7)) * 8)] = v;
    }
  }
}

// ---------------------------------------------------------------------------
// Output GEMM: out[4096][1024] fp32 = attn @ wot^T. BM=64, BN=128, grid (8,64).
// ---------------------------------------------------------------------------
__global__ __launch_bounds__(256, 2) void gemm_wo(
    const unsigned short* __restrict__ A, const unsigned short* __restrict__ Bt,
    float* __restrict__ C)
{
  __shared__ unsigned short sm[24576];
  const int bm = blockIdx.y * 64, bn0 = blockIdx.x;
  const int tid = threadIdx.x;
  const int w = tid >> 6, lane = tid & 63, l16 = lane & 15, quad = lane >> 4;
  const int mh = (w & 1) * 32, nh = (w >> 1) * 64;

  f32_4 acc[2][4];
#pragma unroll
  for (int mt = 0; mt < 2; ++mt)
#pragma unroll
    for (int nt = 0; nt < 4; ++nt) acc[mt][nt] = (f32_4){0.f, 0.f, 0.f, 0.f};

  G64DB_KLOOP(A, Bt);

#pragma unroll
  for (int mt = 0; mt < 2; ++mt)
#pragma unroll
    for (int r = 0; r < 4; ++r) {
      const int row = bm + mh + mt * 16 + quad * 4 + r;
#pragma unroll
      for (int nt = 0; nt < 4; ++nt)
        C[(size_t)row * 1024 + bn0 * 128 + nh + nt * 16 + l16] = acc[mt][nt][r];
    }
}

// ---------------------------------------------------------------------------
// Flash attention v10: key-split wave pairs. v9's counters showed the real
// bottleneck is temporal imbalance: the small co-resident block exits early,
// leaving the big block at 1 wave/SIMD for most of the kernel (Occupancy 11%,
// MfmaUtil 14%). v10: 512-thread blocks, 8 waves = 4 heads x 2 key-parities.
// Wave (par,h) processes tiles par, par+2, ... of head h; partial (acc,l)
// combine by simple addition at the end (no running-max -> linear combine),
// via a 32 KB LDS exchange. Critical path 32 tiles -> 16 steps; main phase
// 4 waves/SIMD, tail 2 waves/SIMD. Both parity tiles staged per step via
// global_load_lds DMA (contiguous 16 KB K + 16 KB V).
// grid 512 (2 blocks/CU, 132 KB LDS/CU); gb = id&7 pins (b,g) to one XCD.
// O aliases qb: reads at entry, writes same region at exit; disjoint across
// blocks; within-block the combine barrier orders reads before writes.
// ---------------------------------------------------------------------------
__global__ __launch_bounds__(512, 4) void flash_attn_v10(
    const unsigned short* __restrict__ Q, const unsigned short* __restrict__ Kimg,
    const unsigned short* __restrict__ Vimg, unsigned short* __restrict__ O)
{
  __shared__ unsigned short Ks[8192];          // [parity][key][d] swizzled
  __shared__ unsigned short Vs[8192];          // [parity][d][key] swizzled
  __shared__ unsigned short Ps[8][2048];       // per-wave [32 q][64 key] swizzled
  __shared__ float lbuf[4][2][64];
  const int id = blockIdx.x;
  const int gb = id & 7;                       // b*4+g -> XCD pin
  const int g = gb & 3, b = gb >> 2;
  const int j = id >> 3;                       // 0..63
  const int qc = (j < 32) ? (63 - j) : (j - 32);   // CU pair sums to 33 tiles
  const int tid = threadIdx.x;
  const int w = tid >> 6, lane = tid & 63, l16 = lane & 15, quad = lane >> 4;
  const int hw = w & 3, par = w >> 2;          // head-in-group, key parity
  const int h = g * 4 + hw;
  const int qbase = qc * 32;
  const int swz = l16 & 7;
  unsigned short* ps = Ps[w];

  // Q B-frags (register-resident): n = q = l16 (+16*qf), k = d = quad*8+j
  bf16_8 bq[2][2];
#pragma unroll
  for (int qf = 0; qf < 2; ++qf) {
    const unsigned short* qp =
        Q + ((size_t)(b * S_LEN + qbase + qf * 16 + l16)) * 1024 + h * 64;
    bq[qf][0] = *(const bf16_8*)(qp + quad * 8);
    bq[qf][1] = *(const bf16_8*)(qp + 32 + quad * 8);
  }

  f32_4 acc[2][4];
#pragma unroll
  for (int qf = 0; qf < 2; ++qf)
#pragma unroll
    for (int mt = 0; mt < 4; ++mt) acc[qf][mt] = (f32_4){0.f, 0.f, 0.f, 0.f};
  float l_part[2] = {0.f, 0.f};

  const unsigned short* kim = Kimg + (size_t)(gb * 32) * 4096;
  const unsigned short* vim = Vimg + (size_t)(gb * 32) * 4096;
  const int ntiles = (qc >> 1) + 1;
  const int steps = (ntiles + 1) >> 1;

  for (int s = 0; s < steps; ++s) {
    __syncthreads();                           // prev compute done reading LDS
    {
      // stage tiles 2s, 2s+1 (contiguous 8192 shorts each of K,V; always
      // in-bounds: 2s+1 <= 31 within the 32-tile image)
      const unsigned short* kp = kim + (size_t)s * 8192;
      const unsigned short* vp = vim + (size_t)s * 8192;
      gll16(kp + tid * 8, &Ks[tid * 8]);
      gll16(kp + (tid + 512) * 8, &Ks[(tid + 512) * 8]);
      gll16(vp + tid * 8, &Vs[tid * 8]);
      gll16(vp + (tid + 512) * 8, &Vs[(tid + 512) * 8]);
    }
    __syncthreads();                           // staging visible (vmcnt drain)

    const int tile = 2 * s + par;
    if (tile < ntiles) {
      const bool diag = (tile == ntiles - 1);
      const unsigned short* ks = Ks + par * 4096;
      const unsigned short* vs = Vs + par * 4096;
      // ---- S^T = K Q^T (row=key, col=q), p = exp2(s), write Ps (b64) ----
#pragma unroll
      for (int mt = 0; mt < 4; ++mt) {
        const int krow = (mt * 16 + l16) * 64;
        const bf16_8 kf0 = *(const bf16_8*)&ks[krow + (quad ^ swz) * 8];
        const bf16_8 kf1 = *(const bf16_8*)&ks[krow + ((4 + quad) ^ swz) * 8];
#pragma unroll
        for (int qf = 0; qf < 2; ++qf) {
          f32_4 z = (f32_4){0.f, 0.f, 0.f, 0.f};
          __builtin_amdgcn_s_setprio(1);
          z = __builtin_amdgcn_mfma_f32_16x16x32_bf16(kf0, bq[qf][0], z, 0, 0, 0);
          z = __builtin_amdgcn_mfma_f32_16x16x32_bf16(kf1, bq[qf][1], z, 0, 0, 0);
          __builtin_amdgcn_s_setprio(0);
          ushort4 pk;
#pragma unroll
          for (int r = 0; r < 4; ++r) {
            float pv = __builtin_amdgcn_exp2f(z[r]);
            if (diag) {
              const int keyl = mt * 16 + quad * 4 + r;
              const int ql = (qc & 1) * 32 + qf * 16 + l16;
              pv = (keyl > ql) ? 0.f : pv;
            }
            l_part[qf] += pv;
            ((unsigned short*)&pk)[r] = ftob(pv);
          }
          // q-row qf*16+l16, keys mt*16+quad*4.. -> chunk 2mt+(quad>>1), swz
          *(ushort4*)&ps[(qf * 16 + l16) * 64 +
                         (((2 * mt + (quad >> 1)) ^ swz) * 8) + (quad & 1) * 4] = pk;
        }
      }
      // ---- P B-frags from Ps (per-wave private; in-wave lgkm ordering) ----
      bf16_8 pf[2][2];
#pragma unroll
      for (int qf = 0; qf < 2; ++qf) {
        const int prow = (qf * 16 + l16) * 64;
        pf[qf][0] = *(const bf16_8*)&ps[prow + ((quad ^ swz) * 8)];
        pf[qf][1] = *(const bf16_8*)&ps[prow + (((4 + quad) ^ swz) * 8)];
      }
      // ---- O^T += V^T @ P^T ----
      __builtin_amdgcn_s_setprio(1);
#pragma unroll
      for (int mt = 0; mt < 4; ++mt) {
        const int vrow = (mt * 16 + l16) * 64;
        const bf16_8 vf0 = *(const bf16_8*)&vs[vrow + (quad ^ swz) * 8];
        const bf16_8 vf1 = *(const bf16_8*)&vs[vrow + ((4 + quad) ^ swz) * 8];
#pragma unroll
        for (int qf = 0; qf < 2; ++qf) {
          acc[qf][mt] = __builtin_amdgcn_mfma_f32_16x16x32_bf16(vf0, pf[qf][0], acc[qf][mt], 0, 0, 0);
          acc[qf][mt] = __builtin_amdgcn_mfma_f32_16x16x32_bf16(vf1, pf[qf][1], acc[qf][mt], 0, 0, 0);
        }
      }
      __builtin_amdgcn_s_setprio(0);
    }
  }

  // ---- combine parity partials: par1 -> LDS, par0 adds (linear combine) ----
  __syncthreads();                             // all compute done; Ps reusable
  float* cb = (float*)&Ps[0][0];               // 4 heads x 2048 floats
  if (par == 1) {
    float* dst = cb + hw * 2048;
#pragma unroll
    for (int qf = 0; qf < 2; ++qf)
#pragma unroll
      for (int mt = 0; mt < 4; ++mt)
#pragma unroll
        for (int r = 0; r < 4; ++r)
          dst[(qf * 16 + mt * 4 + r) * 64 + lane] = acc[qf][mt][r];
    lbuf[hw][0][lane] = l_part[0];
    lbuf[hw][1][lane] = l_part[1];
  }
  __syncthreads();
  if (par == 0) {
    const float* src = cb + hw * 2048;
#pragma unroll
    for (int qf = 0; qf < 2; ++qf)
#pragma unroll
      for (int mt = 0; mt < 4; ++mt)
#pragma unroll
        for (int r = 0; r < 4; ++r)
          acc[qf][mt][r] += src[(qf * 16 + mt * 4 + r) * 64 + lane];
    l_part[0] += lbuf[hw][0][lane];
    l_part[1] += lbuf[hw][1][lane];

    // ---- finalize: l = sum over quads (keys partitioned by quad), write O^T
#pragma unroll
    for (int qf = 0; qf < 2; ++qf) {
      float l = l_part[qf];
      l += __shfl_xor(l, 16);
      l += __shfl_xor(l, 32);
      const float inv = 1.f / l;
      unsigned short* op =
          O + ((size_t)(b * S_LEN + qbase + qf * 16 + l16)) * 1024 + h * 64;
#pragma unroll
      for (int mt = 0; mt < 4; ++mt) {
        ushort4 ov;
#pragma unroll
        for (int r = 0; r < 4; ++r) ((unsigned short*)&ov)[r] = ftob(acc[qf][mt][r] * inv);
        *(ushort4*)&op[mt * 16 + quad * 4] = ov;
      }
    }
  }
}

// ---------------------------------------------------------------------------
extern "C" void kernel_launch(void* const* d_in, const int* in_sizes, int n_in,
                              void* d_out, int out_size, void* d_ws, size_t ws_size,
                              hipStream_t stream)
{
  const float* x    = (const float*)d_in[0];
  const float* cosT = (const float*)d_in[1];
  const float* sinT = (const float*)d_in[2];
  const float* wq   = (const float*)d_in[4];
  const float* wk   = (const float*)d_in[5];
  const float* wv   = (const float*)d_in[6];
  const float* wo   = (const float*)d_in[7];
  float* out = (float*)d_out;

  char* ws = (char*)d_ws;
  const size_t MB = 1024 * 1024;
  unsigned short* xb    = (unsigned short*)(ws);             // 8 MB
  unsigned short* qb    = (unsigned short*)(ws + 8 * MB);    // 8 MB [4096][1024]
  unsigned short* wqkvt = (unsigned short*)(ws + 16 * MB);   // 3 MB [1536][1024]
  unsigned short* Kimg  = (unsigned short*)(ws + 19 * MB);   // 2 MB: 256 x 4096 (swizzled)
  unsigned short* Vimg  = (unsigned short*)(ws + 21 * MB);   // 2 MB: 256 x 4096 (swizzled)
  unsigned short* wot   = (unsigned short*)(ws + 23 * MB);   // 2 MB [1024][1024]
  // total ws use: 25 MB

  prep<<<3584, 256, 0, stream>>>(x, wq, wk, wv, wo, xb, wqkvt, wot);
  gemm_qkv<<<dim3(12, 64), 256, 0, stream>>>(xb, wqkvt, qb, Kimg, Vimg, cosT, sinT);
  flash_attn_v10<<<512, 512, 0, stream>>>(qb, Kimg, Vimg, qb);
  gemm_wo<<<dim3(8, 64), 256, 0, stream>>>(qb, wot, out);
}